// Round 1
// baseline (985.781 us; speedup 1.0000x reference)
//
#include <hip/hip_runtime.h>
#include <cstdint>

#pragma clang fp contract(off)

#define HH 248
#define WW 216
#define HW (HH*WW)          // 53568
#define NROW (HW*6)         // 321408
#define BATCH 16
#define NPRE 100
#define MAXNUM 50
#define NBUCKET 32768
#define CAP 4096
#define PIF 3.14159274101257324f

// ws layout (bytes):
//  [0,                2097152)  hist: 16 x 32768 u32
//  [2097152,          2097216)  cand_count: 16 u32 (padded)
//  [2097216,          2097280)  tb (threshold bucket): 16 u32 (padded)
//  [2097280,          2103680)  sel: 16 x 100 u32
//  [2103680,          2627968)  cand keys: 16 x 4096 u64
#define HIST_BYTES (BATCH*NBUCKET*4)
#define CNT_OFF    HIST_BYTES
#define TB_OFF     (CNT_OFF + 64)
#define SEL_OFF    (TB_OFF + 64)
#define KEYS_OFF   (SEL_OFF + BATCH*NPRE*4)

__device__ __forceinline__ float sigmoidf_ref(float x) {
    // jax.nn.sigmoid-style numerically stable two-branch logistic
    if (x >= 0.0f) {
        return 1.0f / (1.0f + expf(-x));
    } else {
        float e = expf(x);
        return e / (1.0f + e);
    }
}

// ---- Pass 1: histogram of score bit-patterns (scores are in (0,1) so bits are monotone) ----
__global__ void k_hist(const float* __restrict__ cls, unsigned* __restrict__ hist) {
    int cell = blockIdx.x * 256 + threadIdx.x;
    int b = blockIdx.y;
    if (cell >= HW) return;
    const float* p = cls + (size_t)b * 18 * HW + cell;
    unsigned* h = hist + (size_t)b * NBUCKET;
    for (int a = 0; a < 6; ++a) {
        float l0 = p[(a*3+0)*HW];
        float l1 = p[(a*3+1)*HW];
        float l2 = p[(a*3+2)*HW];
        float m = fmaxf(l0, fmaxf(l1, l2));
        float s = sigmoidf_ref(m);          // == max of 3 sigmoids (monotone)
        unsigned bits = __float_as_uint(s);
        unsigned bkt = bits >> 15;
        if (bkt > NBUCKET - 1) bkt = NBUCKET - 1;
        atomicAdd(&h[bkt], 1u);
    }
}

// ---- Pass 2: find threshold bucket tb s.t. count(bucket >= tb) >= 100, minimal coverage ----
__global__ void k_scan(const unsigned* __restrict__ hist, unsigned* __restrict__ tbo) {
    int b = blockIdx.x, t = threadIdx.x;   // 256 threads
    __shared__ unsigned csum[256];
    const unsigned* h = hist + (size_t)b * NBUCKET;
    const int CHUNK = NBUCKET / 256;       // 128
    unsigned s = 0;
    for (int k = 0; k < CHUNK; ++k) s += h[t*CHUNK + k];
    csum[t] = s;
    __syncthreads();
    if (t == 0) {
        unsigned cum = 0;
        int tb = 0;
        for (int u = 255; u >= 0; --u) {
            if (cum + csum[u] >= NPRE) {
                unsigned c2 = cum;
                for (int k2 = (u+1)*CHUNK - 1; k2 >= u*CHUNK; --k2) {
                    c2 += h[k2];
                    if (c2 >= NPRE) { tb = k2; break; }
                }
                break;
            }
            cum += csum[u];
        }
        tbo[b] = (unsigned)tb;
    }
}

// ---- Pass 3: collect all rows with bucket >= tb as sort keys (score desc, index asc) ----
__global__ void k_collect(const float* __restrict__ cls, const unsigned* __restrict__ tbo,
                          unsigned* __restrict__ cnt, unsigned long long* __restrict__ keys) {
    int cell = blockIdx.x * 256 + threadIdx.x;
    int b = blockIdx.y;
    if (cell >= HW) return;
    unsigned tb = tbo[b];
    const float* p = cls + (size_t)b * 18 * HW + cell;
    for (int a = 0; a < 6; ++a) {
        float l0 = p[(a*3+0)*HW];
        float l1 = p[(a*3+1)*HW];
        float l2 = p[(a*3+2)*HW];
        float m = fmaxf(l0, fmaxf(l1, l2));
        float s = sigmoidf_ref(m);
        unsigned bits = __float_as_uint(s);
        unsigned bkt = bits >> 15;
        if (bkt > NBUCKET - 1) bkt = NBUCKET - 1;
        if (bkt >= tb) {
            unsigned pos = atomicAdd(&cnt[b], 1u);
            if (pos < CAP) {
                unsigned row = (unsigned)(cell * 6 + a);
                keys[(size_t)b*CAP + pos] =
                    ((unsigned long long)bits << 32) | (unsigned long long)(0xFFFFFFFFu - row);
            }
        }
    }
}

// ---- Pass 4: exact top-100 of candidates by iterative argmax (keys unique) ----
__global__ void k_top100(const unsigned long long* __restrict__ keys,
                         const unsigned* __restrict__ cnt, unsigned* __restrict__ sel) {
    int b = blockIdx.x, t = threadIdx.x;   // 256 threads
    __shared__ unsigned long long ks[CAP];
    __shared__ unsigned long long red[256];
    unsigned cn = cnt[b];
    int M = (cn < (unsigned)CAP) ? (int)cn : CAP;
    for (int i = t; i < CAP; i += 256) ks[i] = (i < M) ? keys[(size_t)b*CAP + i] : 0ULL;
    __syncthreads();
    for (int r = 0; r < NPRE; ++r) {
        unsigned long long loc = 0ULL;
        for (int i = t; i < CAP; i += 256) { unsigned long long k = ks[i]; if (k > loc) loc = k; }
        red[t] = loc;
        __syncthreads();
        for (int s2 = 128; s2 > 0; s2 >>= 1) {
            if (t < s2) { if (red[t+s2] > red[t]) red[t] = red[t+s2]; }
            __syncthreads();
        }
        unsigned long long mk = red[0];
        // each LDS slot belongs to exactly one thread's stride -> no race on clear
        for (int i = t; i < CAP; i += 256) { if (ks[i] == mk) ks[i] = 0ULL; }
        if (t == 0) sel[b*NPRE + r] = 0xFFFFFFFFu - (unsigned)(mk & 0xFFFFFFFFull);
        __syncthreads();
    }
}

// ---- Pass 5: decode 100 boxes, 3x NMS, final stable top-50, write outputs ----
__global__ __launch_bounds__(128) void k_final(
    const float* __restrict__ cls, const float* __restrict__ box,
    const float* __restrict__ dir, const float* __restrict__ anc,
    const unsigned* __restrict__ sel, float* __restrict__ out) {
    int b = blockIdx.x, t = threadIdx.x;   // 128 threads
    __shared__ float bb[NPRE][7];
    __shared__ float b2d[NPRE][4];
    __shared__ float areaS[NPRE];
    __shared__ float clsS[3][NPRE];
    __shared__ float svals[NPRE];
    __shared__ int   ordS[NPRE];
    __shared__ int   keepS[NPRE];
    __shared__ float flatS[3*NPRE];

    if (t < NPRE) {
        int row = (int)sel[b*NPRE + t];
        int a = row % 6;
        int cell = row / 6;
        const float* cb = cls + (size_t)b * 18 * HW + cell;
        clsS[0][t] = sigmoidf_ref(cb[(a*3+0)*HW]);
        clsS[1][t] = sigmoidf_ref(cb[(a*3+1)*HW]);
        clsS[2][t] = sigmoidf_ref(cb[(a*3+2)*HW]);
        const float* db = dir + (size_t)b * 12 * HW + cell;
        float d0 = db[(a*2+0)*HW];
        float d1 = db[(a*2+1)*HW];
        int dircls = (d1 > d0) ? 1 : 0;    // argmax, first-max-wins ties -> 0
        const float* pb = box + (size_t)b * 42 * HW + cell;
        float dx = pb[(a*7+0)*HW], dy = pb[(a*7+1)*HW], dz = pb[(a*7+2)*HW];
        float dw = pb[(a*7+3)*HW], dl = pb[(a*7+4)*HW], dh = pb[(a*7+5)*HW];
        float dr = pb[(a*7+6)*HW];
        const float* ab = anc + (size_t)row * 7;
        float xa = ab[0], ya = ab[1], za = ab[2];
        float wa = ab[3], la = ab[4], ha = ab[5], ra = ab[6];
        float da = sqrtf(wa*wa + la*la);
        float x = dx*da + xa;
        float y = dy*da + ya;
        float z = dz*ha + za + ha*0.5f;
        float wv = wa*expf(dw);
        float lv = la*expf(dl);
        float hv = ha*expf(dh);
        z = z - hv*0.5f;
        float th0 = ra + dr;
        float lim = th0 - floorf(th0/PIF + 1.0f)*PIF;     // limit_period
        float theta = lim + (1.0f - (float)dircls)*PIF;
        bb[t][0]=x; bb[t][1]=y; bb[t][2]=z; bb[t][3]=wv; bb[t][4]=lv; bb[t][5]=hv; bb[t][6]=theta;
        b2d[t][0] = x - wv*0.5f;
        b2d[t][1] = y - lv*0.5f;
        b2d[t][2] = x + wv*0.5f;
        b2d[t][3] = y + lv*0.5f;
        areaS[t] = (b2d[t][2]-b2d[t][0]) * (b2d[t][3]-b2d[t][1]);
    }
    __syncthreads();

    for (int c = 0; c < 3; ++c) {
        int r = 0;
        if (t < NPRE) {
            float sc = clsS[c][t];
            bool valid = sc > 0.1f;
            svals[t] = valid ? sc : -INFINITY;
        }
        __syncthreads();
        if (t < NPRE) {
            float vt = svals[t];
            for (int j = 0; j < NPRE; ++j) {
                float vj = svals[j];
                if (vj > vt || (vj == vt && j < t)) ++r;   // stable descending rank
            }
            ordS[r] = t;
            keepS[r] = (svals[t] != -INFINITY) ? 1 : 0;    // = valid in sorted order
        }
        __syncthreads();
        for (int i = 0; i < NPRE-1; ++i) {
            if (keepS[i] && t > i && t < NPRE) {
                int bi = ordS[i], bt = ordS[t];
                float x1 = fmaxf(b2d[bi][0], b2d[bt][0]);
                float y1 = fmaxf(b2d[bi][1], b2d[bt][1]);
                float x2 = fminf(b2d[bi][2], b2d[bt][2]);
                float y2 = fminf(b2d[bi][3], b2d[bt][3]);
                float inter = fmaxf(x2 - x1, 0.0f) * fmaxf(y2 - y1, 0.0f);
                float iou = inter / (areaS[bi] + areaS[bt] - inter + 1e-8f);
                if (iou > 0.01f) keepS[t] = 0;
            }
            __syncthreads();
        }
        if (t < NPRE) {
            flatS[c*NPRE + t] = (keepS[r] != 0) ? clsS[c][t] : -1.0f;
        }
        __syncthreads();
    }

    // stable top-50 over 300 flat entries; ranks are unique -> each output slot written once
    for (int i = t; i < 3*NPRE; i += 128) {
        float vi = flatS[i];
        int r2 = 0;
        for (int j = 0; j < 3*NPRE; ++j) {
            float vj = flatS[j];
            if (vj > vi || (vj == vi && j < i)) ++r2;
        }
        if (r2 < MAXNUM) {
            int p = i % NPRE;
            int lab = i / NPRE;
            int o = b*MAXNUM + r2;
            float* ob = out + (size_t)o * 7;
            for (int j = 0; j < 7; ++j) ob[j] = bb[p][j];
            out[BATCH*MAXNUM*7 + o] = (float)lab;          // labels
            out[BATCH*MAXNUM*8 + o] = vi;                  // final_scores
            out[BATCH*MAXNUM*9 + o] = (vi > 0.0f) ? 1.0f : 0.0f; // mask
        }
    }
}

extern "C" void kernel_launch(void* const* d_in, const int* in_sizes, int n_in,
                              void* d_out, int out_size, void* d_ws, size_t ws_size,
                              hipStream_t stream) {
    const float* cls = (const float*)d_in[0];
    const float* box = (const float*)d_in[1];
    const float* dir = (const float*)d_in[2];
    const float* anc = (const float*)d_in[3];
    float* out = (float*)d_out;
    char* ws = (char*)d_ws;

    unsigned* hist = (unsigned*)(ws + 0);
    unsigned* cnt  = (unsigned*)(ws + CNT_OFF);
    unsigned* tb   = (unsigned*)(ws + TB_OFF);
    unsigned* sel  = (unsigned*)(ws + SEL_OFF);
    unsigned long long* keys = (unsigned long long*)(ws + KEYS_OFF);

    // zero histogram + candidate counters (ws is poisoned 0xAA before every call)
    hipMemsetAsync(ws, 0, (size_t)(CNT_OFF + 64), stream);

    dim3 g1((HW + 255) / 256, BATCH);
    k_hist   <<<g1, 256, 0, stream>>>(cls, hist);
    k_scan   <<<BATCH, 256, 0, stream>>>(hist, tb);
    k_collect<<<g1, 256, 0, stream>>>(cls, tb, cnt, keys);
    k_top100 <<<BATCH, 256, 0, stream>>>(keys, cnt, sel);
    k_final  <<<BATCH, 128, 0, stream>>>(cls, box, dir, anc, sel, out);
}

// Round 2
// 362.052 us; speedup vs baseline: 2.7228x; 2.7228x over previous
//
#include <hip/hip_runtime.h>
#include <cstdint>

#pragma clang fp contract(off)

#define HH 248
#define WW 216
#define HW (HH*WW)          // 53568 cells (divisible by 4)
#define BATCH 16
#define NPRE 100
#define MAXNUM 50
#define NB 2048             // buckets = score_bits >> 19 ; max 2032 for s in (0,1]
#define CAP 2048
#define SBLK 53             // ceil(53568 / 1024) blocks per batch
#define PIF 3.14159274101257324f

// ws layout (bytes):
//  [0,      64)                    cnt: 16 u32 (memset 0 each call)
//  [64,     128)                   tb : 16 u32
//  [128,    128+16*2048*8)         cand keys: 16 x CAP u64          (262144 B)
//  [262272, 262272+16*53*2048*2)   subhist u16: [b][blk][bucket]    (3473408 B)
#define CNT_OFF  0
#define TB_OFF   64
#define KEYS_OFF 128
#define SH_OFF   (KEYS_OFF + BATCH*CAP*8)

__device__ __forceinline__ float sigmoidf_ref(float x) {
    if (x >= 0.0f) {
        return 1.0f / (1.0f + expf(-x));
    } else {
        float e = expf(x);
        return e / (1.0f + e);
    }
}

// ---- Pass 1: per-block LDS histogram of score buckets; no global atomics ----
__global__ __launch_bounds__(256) void k_score(const float* __restrict__ cls,
                                               unsigned short* __restrict__ subhist) {
    int t = threadIdx.x, blk = blockIdx.x, b = blockIdx.y;
    __shared__ unsigned hist[NB];
    for (int i = t; i < NB; i += 256) hist[i] = 0;
    __syncthreads();

    int cell0 = blk * 1024 + t * 4;
    if (cell0 < HW) {
        const float* p = cls + (size_t)b * 18 * HW;
        for (int a = 0; a < 6; ++a) {
            float4 l0 = *(const float4*)(p + (size_t)(a*3+0)*HW + cell0);
            float4 l1 = *(const float4*)(p + (size_t)(a*3+1)*HW + cell0);
            float4 l2 = *(const float4*)(p + (size_t)(a*3+2)*HW + cell0);
            float m0 = fmaxf(l0.x, fmaxf(l1.x, l2.x));
            float m1 = fmaxf(l0.y, fmaxf(l1.y, l2.y));
            float m2 = fmaxf(l0.z, fmaxf(l1.z, l2.z));
            float m3 = fmaxf(l0.w, fmaxf(l1.w, l2.w));
            atomicAdd(&hist[__float_as_uint(sigmoidf_ref(m0)) >> 19], 1u);
            atomicAdd(&hist[__float_as_uint(sigmoidf_ref(m1)) >> 19], 1u);
            atomicAdd(&hist[__float_as_uint(sigmoidf_ref(m2)) >> 19], 1u);
            atomicAdd(&hist[__float_as_uint(sigmoidf_ref(m3)) >> 19], 1u);
        }
    }
    __syncthreads();
    unsigned short* sh = subhist + (size_t)(b * SBLK + blk) * NB;
    for (int i = t; i < NB; i += 256) sh[i] = (unsigned short)hist[i];
}

// ---- Pass 2: per-batch reduce of sub-hists + threshold-bucket scan ----
__global__ __launch_bounds__(256) void k_reduce(const unsigned short* __restrict__ subhist,
                                                unsigned* __restrict__ tbo) {
    int b = blockIdx.x, t = threadIdx.x;
    __shared__ unsigned h[NB];
    const unsigned short* base = subhist + (size_t)b * SBLK * NB;
    for (int j = t; j < NB; j += 256) {
        unsigned s = 0;
        for (int k = 0; k < SBLK; ++k) s += base[(size_t)k * NB + j];
        h[j] = s;
    }
    __syncthreads();
    if (t == 0) {
        unsigned cum = 0;
        int r = NB - 1;
        for (; r >= 0; --r) { cum += h[r]; if (cum >= NPRE) break; }
        tbo[b] = (unsigned)(r < 0 ? 0 : r);
    }
}

// ---- Pass 3: collect candidate keys (score_bits desc, row asc); ~300 atomics total ----
__global__ __launch_bounds__(256) void k_collect(const float* __restrict__ cls,
                                                 const unsigned* __restrict__ tbo,
                                                 unsigned* __restrict__ cnt,
                                                 unsigned long long* __restrict__ keys) {
    int t = threadIdx.x, blk = blockIdx.x, b = blockIdx.y;
    int cell0 = blk * 1024 + t * 4;
    if (cell0 >= HW) return;
    unsigned tb = tbo[b];
    const float* p = cls + (size_t)b * 18 * HW;
    for (int a = 0; a < 6; ++a) {
        float4 l0 = *(const float4*)(p + (size_t)(a*3+0)*HW + cell0);
        float4 l1 = *(const float4*)(p + (size_t)(a*3+1)*HW + cell0);
        float4 l2 = *(const float4*)(p + (size_t)(a*3+2)*HW + cell0);
        float m[4];
        m[0] = fmaxf(l0.x, fmaxf(l1.x, l2.x));
        m[1] = fmaxf(l0.y, fmaxf(l1.y, l2.y));
        m[2] = fmaxf(l0.z, fmaxf(l1.z, l2.z));
        m[3] = fmaxf(l0.w, fmaxf(l1.w, l2.w));
        for (int e = 0; e < 4; ++e) {
            unsigned bits = __float_as_uint(sigmoidf_ref(m[e]));
            if ((bits >> 19) >= tb) {
                unsigned pos = atomicAdd(&cnt[b], 1u);
                if (pos < CAP) {
                    unsigned row = (unsigned)((cell0 + e) * 6 + a);
                    keys[(size_t)b * CAP + pos] =
                        ((unsigned long long)bits << 32) |
                        (unsigned long long)(0xFFFFFFFFu - row);
                }
            }
        }
    }
}

// ---- Pass 4: top-100 rank-select, decode, 3x NMS (bitmask + serial walk), top-50 ----
__global__ __launch_bounds__(256) void k_final(
    const float* __restrict__ cls, const float* __restrict__ box,
    const float* __restrict__ dir, const float* __restrict__ anc,
    const unsigned* __restrict__ cnt, const unsigned long long* __restrict__ keys,
    float* __restrict__ out) {
    int b = blockIdx.x, t = threadIdx.x;   // 256 threads

    __shared__ unsigned long long keyS[CAP];           // 16 KB
    __shared__ int   selRow[NPRE];
    __shared__ float bb[NPRE][7];
    __shared__ float b2d[NPRE][4];
    __shared__ float areaS[NPRE];
    __shared__ float clsS[3][NPRE];
    __shared__ float svalS[3][NPRE];
    __shared__ int   ordS[3][NPRE];
    __shared__ int   rankS[3][NPRE];
    __shared__ unsigned keepInit[3][4];
    __shared__ unsigned long long maskS[3][NPRE][2];   // 4.8 KB
    __shared__ unsigned long long keepBits[3][2];
    __shared__ float flatS[3*NPRE];

    unsigned cn = cnt[b];
    int M = (cn < (unsigned)CAP) ? (int)cn : CAP;
    for (int i = t; i < CAP; i += 256)
        keyS[i] = (i < M) ? keys[(size_t)b * CAP + i] : 0ULL;
    __syncthreads();

    // exact top-100: keys unique -> ranks unique
    for (int i = t; i < M; i += 256) {
        unsigned long long k = keyS[i];
        int r = 0;
        for (int j = 0; j < M; ++j) r += (keyS[j] > k);
        if (r < NPRE) selRow[r] = (int)(0xFFFFFFFFu - (unsigned)(k & 0xFFFFFFFFull));
    }
    __syncthreads();

    // decode the 100 selected rows
    if (t < NPRE) {
        int row = selRow[t];
        int a = row % 6;
        int cell = row / 6;
        const float* cb = cls + (size_t)b * 18 * HW + cell;
        clsS[0][t] = sigmoidf_ref(cb[(size_t)(a*3+0)*HW]);
        clsS[1][t] = sigmoidf_ref(cb[(size_t)(a*3+1)*HW]);
        clsS[2][t] = sigmoidf_ref(cb[(size_t)(a*3+2)*HW]);
        const float* db = dir + (size_t)b * 12 * HW + cell;
        float d0 = db[(size_t)(a*2+0)*HW];
        float d1 = db[(size_t)(a*2+1)*HW];
        int dircls = (d1 > d0) ? 1 : 0;
        const float* pb = box + (size_t)b * 42 * HW + cell;
        float dx = pb[(size_t)(a*7+0)*HW], dy = pb[(size_t)(a*7+1)*HW], dz = pb[(size_t)(a*7+2)*HW];
        float dw = pb[(size_t)(a*7+3)*HW], dl = pb[(size_t)(a*7+4)*HW], dh = pb[(size_t)(a*7+5)*HW];
        float dr = pb[(size_t)(a*7+6)*HW];
        const float* ab = anc + (size_t)row * 7;
        float xa = ab[0], ya = ab[1], za = ab[2];
        float wa = ab[3], la = ab[4], ha = ab[5], ra = ab[6];
        float da = sqrtf(wa*wa + la*la);
        float x = dx*da + xa;
        float y = dy*da + ya;
        float z = dz*ha + za + ha*0.5f;
        float wv = wa*expf(dw);
        float lv = la*expf(dl);
        float hv = ha*expf(dh);
        z = z - hv*0.5f;
        float th0 = ra + dr;
        float lim = th0 - floorf(th0/PIF + 1.0f)*PIF;
        float theta = lim + (1.0f - (float)dircls)*PIF;
        bb[t][0]=x; bb[t][1]=y; bb[t][2]=z; bb[t][3]=wv; bb[t][4]=lv; bb[t][5]=hv; bb[t][6]=theta;
        b2d[t][0] = x - wv*0.5f;
        b2d[t][1] = y - lv*0.5f;
        b2d[t][2] = x + wv*0.5f;
        b2d[t][3] = y + lv*0.5f;
        areaS[t] = (b2d[t][2]-b2d[t][0]) * (b2d[t][3]-b2d[t][1]);
    }
    if (t < 12) keepInit[t/4][t%4] = 0u;
    __syncthreads();

    // masked scores
    for (int w = t; w < 3*NPRE; w += 256) {
        int c = w / NPRE, p = w % NPRE;
        float sc = clsS[c][p];
        svalS[c][p] = (sc > 0.1f) ? sc : -INFINITY;
    }
    __syncthreads();

    // stable descending rank per class (ties -> lower index first, matches stable argsort)
    for (int w = t; w < 3*NPRE; w += 256) {
        int c = w / NPRE, p = w % NPRE;
        float v = svalS[c][p];
        int r = 0;
        for (int j = 0; j < NPRE; ++j) {
            float vj = svalS[c][j];
            if (vj > v || (vj == v && j < p)) ++r;
        }
        ordS[c][r] = p;
        rankS[c][p] = r;
        if (v != -INFINITY) atomicOr(&keepInit[c][r >> 5], 1u << (r & 31));
    }
    __syncthreads();

    // pairwise suppression masks in sorted space (j > i, iou > thr)
    for (int w = t; w < 3*NPRE; w += 256) {
        int c = w / NPRE, i = w % NPRE;
        int pi = ordS[c][i];
        unsigned long long m0 = 0ULL, m1 = 0ULL;
        float ax1 = b2d[pi][0], ay1 = b2d[pi][1], ax2 = b2d[pi][2], ay2 = b2d[pi][3];
        float ai = areaS[pi];
        for (int j = i + 1; j < NPRE; ++j) {
            int pj = ordS[c][j];
            float x1 = fmaxf(ax1, b2d[pj][0]);
            float y1 = fmaxf(ay1, b2d[pj][1]);
            float x2 = fminf(ax2, b2d[pj][2]);
            float y2 = fminf(ay2, b2d[pj][3]);
            float inter = fmaxf(x2 - x1, 0.0f) * fmaxf(y2 - y1, 0.0f);
            float iou = inter / (ai + areaS[pj] - inter + 1e-8f);
            if (iou > 0.01f) {
                if (j < 64) m0 |= (1ULL << j);
                else        m1 |= (1ULL << (j - 64));
            }
        }
        maskS[c][i][0] = m0;
        maskS[c][i][1] = m1;
    }
    __syncthreads();

    // greedy serial walk, one lane per class (same code path -> no divergence)
    if (t < 3) {
        int c = t;
        unsigned long long k0 = (unsigned long long)keepInit[c][0] |
                                ((unsigned long long)keepInit[c][1] << 32);
        unsigned long long k1 = (unsigned long long)keepInit[c][2] |
                                ((unsigned long long)keepInit[c][3] << 32);
        for (int i = 0; i < NPRE; ++i) {
            unsigned long long bit = (i < 64) ? (k0 >> i) : (k1 >> (i - 64));
            if (bit & 1ULL) {
                k0 &= ~maskS[c][i][0];
                k1 &= ~maskS[c][i][1];
            }
        }
        keepBits[c][0] = k0;
        keepBits[c][1] = k1;
    }
    __syncthreads();

    // flat masked score array (keep already includes validity)
    for (int w = t; w < 3*NPRE; w += 256) {
        int c = w / NPRE, p = w % NPRE;
        int r = rankS[c][p];
        unsigned long long bit = (r < 64) ? (keepBits[c][0] >> r) : (keepBits[c][1] >> (r - 64));
        flatS[w] = (bit & 1ULL) ? clsS[c][p] : -1.0f;
    }
    __syncthreads();

    // stable top-50 over 300 entries; ranks unique -> each slot written exactly once
    for (int i = t; i < 3*NPRE; i += 256) {
        float vi = flatS[i];
        int r2 = 0;
        for (int j = 0; j < 3*NPRE; ++j) {
            float vj = flatS[j];
            if (vj > vi || (vj == vi && j < i)) ++r2;
        }
        if (r2 < MAXNUM) {
            int p = i % NPRE;
            int lab = i / NPRE;
            int o = b * MAXNUM + r2;
            float* ob = out + (size_t)o * 7;
            for (int j = 0; j < 7; ++j) ob[j] = bb[p][j];
            out[BATCH*MAXNUM*7 + o] = (float)lab;
            out[BATCH*MAXNUM*8 + o] = vi;
            out[BATCH*MAXNUM*9 + o] = (vi > 0.0f) ? 1.0f : 0.0f;
        }
    }
}

extern "C" void kernel_launch(void* const* d_in, const int* in_sizes, int n_in,
                              void* d_out, int out_size, void* d_ws, size_t ws_size,
                              hipStream_t stream) {
    const float* cls = (const float*)d_in[0];
    const float* box = (const float*)d_in[1];
    const float* dir = (const float*)d_in[2];
    const float* anc = (const float*)d_in[3];
    float* out = (float*)d_out;
    char* ws = (char*)d_ws;

    unsigned* cnt = (unsigned*)(ws + CNT_OFF);
    unsigned* tb  = (unsigned*)(ws + TB_OFF);
    unsigned long long* keys = (unsigned long long*)(ws + KEYS_OFF);
    unsigned short* subhist  = (unsigned short*)(ws + SH_OFF);

    hipMemsetAsync(cnt, 0, 64, stream);

    dim3 g(SBLK, BATCH);
    k_score  <<<g, 256, 0, stream>>>(cls, subhist);
    k_reduce <<<BATCH, 256, 0, stream>>>(subhist, tb);
    k_collect<<<g, 256, 0, stream>>>(cls, tb, cnt, keys);
    k_final  <<<BATCH, 256, 0, stream>>>(cls, box, dir, anc, cnt, keys, out);
}

// Round 3
// 352.699 us; speedup vs baseline: 2.7950x; 1.0265x over previous
//
#include <hip/hip_runtime.h>
#include <cstdint>

#pragma clang fp contract(off)

#define HH 248
#define WW 216
#define HW (HH*WW)          // 53568 cells (divisible by 4)
#define NROW (6*HW)         // 321408
#define BATCH 16
#define NPRE 100
#define MAXNUM 50
#define NB 4096             // two-level buckets: fine for s>=0.5, coarse below
#define CAP 2048
#define CPB 4096            // cells per k_score block
#define SBLK 14             // ceil(53568/4096)
#define CBLK 314            // ceil(321408/1024) collect blocks per batch
#define PIF 3.14159274101257324f

// ws layout (bytes):
//  [0,       64)        cnt: 16 u32 (memset 0 each call)
//  [64,      128)       tb : 16 u32
//  [128,     262272)    cand keys: 16 x CAP u64
//  [262272,  2097280)   subhist u16: [b][SBLK][NB]
//  [2097280, 22667392)  scorebits u32: [b][a*HW+cell]
#define CNT_OFF  0
#define TB_OFF   64
#define KEYS_OFF 128
#define SH_OFF   (KEYS_OFF + BATCH*CAP*8)
#define SB_OFF   (SH_OFF + BATCH*SBLK*NB*2)

__device__ __forceinline__ float sigmoidf_ref(float x) {
    if (x >= 0.0f) {
        return 1.0f / (1.0f + expf(-x));
    } else {
        float e = expf(x);
        return e / (1.0f + e);
    }
}

// monotone (non-decreasing) bucket of positive-float score bits
__device__ __forceinline__ unsigned bucket_of(unsigned bits) {
    unsigned b = (bits >= 0x3F000000u) ? (2048u + ((bits - 0x3F000000u) >> 12))
                                       : (bits >> 19);
    return (b > (unsigned)(NB - 1)) ? (unsigned)(NB - 1) : b;
}

// ---- Pass 1: score + store score bits + fine LDS histogram (contention-free) ----
__global__ __launch_bounds__(256) void k_score(const float* __restrict__ cls,
                                               unsigned* __restrict__ sb,
                                               unsigned short* __restrict__ subhist) {
    int t = threadIdx.x, blk = blockIdx.x, b = blockIdx.y;
    __shared__ unsigned hist[NB];   // 16 KB
    for (int i = t; i < NB; i += 256) hist[i] = 0;
    __syncthreads();

    const float* p = cls + (size_t)b * 18 * HW;
    unsigned* sbb = sb + (size_t)b * NROW;

    for (int k = 0; k < 4; ++k) {
        int cell0 = blk * CPB + k * 1024 + t * 4;
        if (cell0 < HW) {           // HW%4==0 and cell0%4==0 -> full float4 in-bounds
            for (int a = 0; a < 6; ++a) {
                float4 l0 = *(const float4*)(p + (size_t)(a*3+0)*HW + cell0);
                float4 l1 = *(const float4*)(p + (size_t)(a*3+1)*HW + cell0);
                float4 l2 = *(const float4*)(p + (size_t)(a*3+2)*HW + cell0);
                unsigned b0 = __float_as_uint(sigmoidf_ref(fmaxf(l0.x, fmaxf(l1.x, l2.x))));
                unsigned b1 = __float_as_uint(sigmoidf_ref(fmaxf(l0.y, fmaxf(l1.y, l2.y))));
                unsigned b2 = __float_as_uint(sigmoidf_ref(fmaxf(l0.z, fmaxf(l1.z, l2.z))));
                unsigned b3 = __float_as_uint(sigmoidf_ref(fmaxf(l0.w, fmaxf(l1.w, l2.w))));
                atomicAdd(&hist[bucket_of(b0)], 1u);
                atomicAdd(&hist[bucket_of(b1)], 1u);
                atomicAdd(&hist[bucket_of(b2)], 1u);
                atomicAdd(&hist[bucket_of(b3)], 1u);
                uint4 v; v.x = b0; v.y = b1; v.z = b2; v.w = b3;
                *(uint4*)(sbb + (size_t)a*HW + cell0) = v;
            }
        }
    }
    __syncthreads();
    unsigned short* sh = subhist + (size_t)(b * SBLK + blk) * NB;
    for (int i = t; i < NB; i += 256) sh[i] = (unsigned short)hist[i];
}

// ---- Pass 2: per-batch reduce of sub-hists + threshold-bucket scan ----
__global__ __launch_bounds__(256) void k_reduce(const unsigned short* __restrict__ subhist,
                                                unsigned* __restrict__ tbo) {
    int b = blockIdx.x, t = threadIdx.x;
    __shared__ unsigned h[NB];
    __shared__ unsigned csum[256];
    const unsigned short* base = subhist + (size_t)b * SBLK * NB;
    for (int j = t; j < NB; j += 256) {
        unsigned s = 0;
        for (int k = 0; k < SBLK; ++k) s += base[(size_t)k * NB + j];
        h[j] = s;
    }
    __syncthreads();
    unsigned cs = 0;
    for (int q = 0; q < 16; ++q) cs += h[t * 16 + q];
    csum[t] = cs;
    __syncthreads();
    if (t == 0) {
        unsigned cum = 0;
        int r = 0;
        for (int u = 255; u >= 0; --u) {
            if (cum + csum[u] >= NPRE) {
                unsigned c2 = cum;
                for (int k2 = (u + 1) * 16 - 1; k2 >= u * 16; --k2) {
                    c2 += h[k2];
                    if (c2 >= NPRE) { r = k2; break; }
                }
                break;
            }
            cum += csum[u];
        }
        tbo[b] = (unsigned)r;
    }
}

// ---- Pass 3: scan stored score bits, collect candidate keys ----
__global__ __launch_bounds__(256) void k_collect(const unsigned* __restrict__ sb,
                                                 const unsigned* __restrict__ tbo,
                                                 unsigned* __restrict__ cnt,
                                                 unsigned long long* __restrict__ keys) {
    int t = threadIdx.x, blk = blockIdx.x, b = blockIdx.y;
    int i0 = blk * 1024 + t * 4;
    if (i0 >= NROW) return;         // NROW%4==0 -> full uint4 in-bounds
    unsigned tb = tbo[b];
    uint4 v = *(const uint4*)(sb + (size_t)b * NROW + i0);
    unsigned bs[4] = {v.x, v.y, v.z, v.w};
    for (int e = 0; e < 4; ++e) {
        unsigned bits = bs[e];
        if (bucket_of(bits) >= tb) {
            unsigned pos = atomicAdd(&cnt[b], 1u);
            if (pos < CAP) {
                int i = i0 + e;
                int a = i / HW;
                int cell = i - a * HW;
                unsigned row = (unsigned)(cell * 6 + a);
                keys[(size_t)b * CAP + pos] =
                    ((unsigned long long)bits << 32) |
                    (unsigned long long)(0xFFFFFFFFu - row);
            }
        }
    }
}

// ---- Pass 4: top-100 rank-select, decode, 3x NMS (bitmask + serial walk), top-50 ----
__global__ __launch_bounds__(256) void k_final(
    const float* __restrict__ cls, const float* __restrict__ box,
    const float* __restrict__ dir, const float* __restrict__ anc,
    const unsigned* __restrict__ cnt, const unsigned long long* __restrict__ keys,
    float* __restrict__ out) {
    int b = blockIdx.x, t = threadIdx.x;   // 256 threads

    __shared__ unsigned long long keyS[CAP];           // 16 KB
    __shared__ int   selRow[NPRE];
    __shared__ float bb[NPRE][7];
    __shared__ float b2d[NPRE][4];
    __shared__ float areaS[NPRE];
    __shared__ float clsS[3][NPRE];
    __shared__ float svalS[3][NPRE];
    __shared__ int   ordS[3][NPRE];
    __shared__ int   rankS[3][NPRE];
    __shared__ unsigned keepInit[3][4];
    __shared__ unsigned long long maskS[3][NPRE][2];
    __shared__ unsigned long long keepBits[3][2];
    __shared__ float flatS[3*NPRE];

    unsigned cn = cnt[b];
    int M = (cn < (unsigned)CAP) ? (int)cn : CAP;
    for (int i = t; i < CAP; i += 256)
        keyS[i] = (i < M) ? keys[(size_t)b * CAP + i] : 0ULL;
    __syncthreads();

    // exact top-100: keys unique -> ranks unique
    for (int i = t; i < M; i += 256) {
        unsigned long long k = keyS[i];
        int r = 0;
        for (int j = 0; j < M; ++j) r += (keyS[j] > k);
        if (r < NPRE) selRow[r] = (int)(0xFFFFFFFFu - (unsigned)(k & 0xFFFFFFFFull));
    }
    __syncthreads();

    // decode the 100 selected rows
    if (t < NPRE) {
        int row = selRow[t];
        int a = row % 6;
        int cell = row / 6;
        const float* cb = cls + (size_t)b * 18 * HW + cell;
        clsS[0][t] = sigmoidf_ref(cb[(size_t)(a*3+0)*HW]);
        clsS[1][t] = sigmoidf_ref(cb[(size_t)(a*3+1)*HW]);
        clsS[2][t] = sigmoidf_ref(cb[(size_t)(a*3+2)*HW]);
        const float* db = dir + (size_t)b * 12 * HW + cell;
        float d0 = db[(size_t)(a*2+0)*HW];
        float d1 = db[(size_t)(a*2+1)*HW];
        int dircls = (d1 > d0) ? 1 : 0;
        const float* pb = box + (size_t)b * 42 * HW + cell;
        float dx = pb[(size_t)(a*7+0)*HW], dy = pb[(size_t)(a*7+1)*HW], dz = pb[(size_t)(a*7+2)*HW];
        float dw = pb[(size_t)(a*7+3)*HW], dl = pb[(size_t)(a*7+4)*HW], dh = pb[(size_t)(a*7+5)*HW];
        float dr = pb[(size_t)(a*7+6)*HW];
        const float* ab = anc + (size_t)row * 7;
        float xa = ab[0], ya = ab[1], za = ab[2];
        float wa = ab[3], la = ab[4], ha = ab[5], ra = ab[6];
        float da = sqrtf(wa*wa + la*la);
        float x = dx*da + xa;
        float y = dy*da + ya;
        float z = dz*ha + za + ha*0.5f;
        float wv = wa*expf(dw);
        float lv = la*expf(dl);
        float hv = ha*expf(dh);
        z = z - hv*0.5f;
        float th0 = ra + dr;
        float lim = th0 - floorf(th0/PIF + 1.0f)*PIF;
        float theta = lim + (1.0f - (float)dircls)*PIF;
        bb[t][0]=x; bb[t][1]=y; bb[t][2]=z; bb[t][3]=wv; bb[t][4]=lv; bb[t][5]=hv; bb[t][6]=theta;
        b2d[t][0] = x - wv*0.5f;
        b2d[t][1] = y - lv*0.5f;
        b2d[t][2] = x + wv*0.5f;
        b2d[t][3] = y + lv*0.5f;
        areaS[t] = (b2d[t][2]-b2d[t][0]) * (b2d[t][3]-b2d[t][1]);
    }
    if (t < 12) keepInit[t/4][t%4] = 0u;
    __syncthreads();

    // masked scores
    for (int w = t; w < 3*NPRE; w += 256) {
        int c = w / NPRE, p = w % NPRE;
        float sc = clsS[c][p];
        svalS[c][p] = (sc > 0.1f) ? sc : -INFINITY;
    }
    __syncthreads();

    // stable descending rank per class (ties -> lower index first)
    for (int w = t; w < 3*NPRE; w += 256) {
        int c = w / NPRE, p = w % NPRE;
        float v = svalS[c][p];
        int r = 0;
        for (int j = 0; j < NPRE; ++j) {
            float vj = svalS[c][j];
            if (vj > v || (vj == v && j < p)) ++r;
        }
        ordS[c][r] = p;
        rankS[c][p] = r;
        if (v != -INFINITY) atomicOr(&keepInit[c][r >> 5], 1u << (r & 31));
    }
    __syncthreads();

    // pairwise suppression masks in sorted space (j > i, iou > thr)
    for (int w = t; w < 3*NPRE; w += 256) {
        int c = w / NPRE, i = w % NPRE;
        int pi = ordS[c][i];
        unsigned long long m0 = 0ULL, m1 = 0ULL;
        float ax1 = b2d[pi][0], ay1 = b2d[pi][1], ax2 = b2d[pi][2], ay2 = b2d[pi][3];
        float ai = areaS[pi];
        for (int j = i + 1; j < NPRE; ++j) {
            int pj = ordS[c][j];
            float x1 = fmaxf(ax1, b2d[pj][0]);
            float y1 = fmaxf(ay1, b2d[pj][1]);
            float x2 = fminf(ax2, b2d[pj][2]);
            float y2 = fminf(ay2, b2d[pj][3]);
            float inter = fmaxf(x2 - x1, 0.0f) * fmaxf(y2 - y1, 0.0f);
            float iou = inter / (ai + areaS[pj] - inter + 1e-8f);
            if (iou > 0.01f) {
                if (j < 64) m0 |= (1ULL << j);
                else        m1 |= (1ULL << (j - 64));
            }
        }
        maskS[c][i][0] = m0;
        maskS[c][i][1] = m1;
    }
    __syncthreads();

    // greedy serial walk, one lane per class
    if (t < 3) {
        int c = t;
        unsigned long long k0 = (unsigned long long)keepInit[c][0] |
                                ((unsigned long long)keepInit[c][1] << 32);
        unsigned long long k1 = (unsigned long long)keepInit[c][2] |
                                ((unsigned long long)keepInit[c][3] << 32);
        for (int i = 0; i < NPRE; ++i) {
            unsigned long long bit = (i < 64) ? (k0 >> i) : (k1 >> (i - 64));
            if (bit & 1ULL) {
                k0 &= ~maskS[c][i][0];
                k1 &= ~maskS[c][i][1];
            }
        }
        keepBits[c][0] = k0;
        keepBits[c][1] = k1;
    }
    __syncthreads();

    // flat masked score array (keep already includes validity)
    for (int w = t; w < 3*NPRE; w += 256) {
        int c = w / NPRE, p = w % NPRE;
        int r = rankS[c][p];
        unsigned long long bit = (r < 64) ? (keepBits[c][0] >> r) : (keepBits[c][1] >> (r - 64));
        flatS[w] = (bit & 1ULL) ? clsS[c][p] : -1.0f;
    }
    __syncthreads();

    // stable top-50 over 300 entries; ranks unique -> each slot written exactly once
    for (int i = t; i < 3*NPRE; i += 256) {
        float vi = flatS[i];
        int r2 = 0;
        for (int j = 0; j < 3*NPRE; ++j) {
            float vj = flatS[j];
            if (vj > vi || (vj == vi && j < i)) ++r2;
        }
        if (r2 < MAXNUM) {
            int p = i % NPRE;
            int lab = i / NPRE;
            int o = b * MAXNUM + r2;
            float* ob = out + (size_t)o * 7;
            for (int j = 0; j < 7; ++j) ob[j] = bb[p][j];
            out[BATCH*MAXNUM*7 + o] = (float)lab;
            out[BATCH*MAXNUM*8 + o] = vi;
            out[BATCH*MAXNUM*9 + o] = (vi > 0.0f) ? 1.0f : 0.0f;
        }
    }
}

extern "C" void kernel_launch(void* const* d_in, const int* in_sizes, int n_in,
                              void* d_out, int out_size, void* d_ws, size_t ws_size,
                              hipStream_t stream) {
    const float* cls = (const float*)d_in[0];
    const float* box = (const float*)d_in[1];
    const float* dir = (const float*)d_in[2];
    const float* anc = (const float*)d_in[3];
    float* out = (float*)d_out;
    char* ws = (char*)d_ws;

    unsigned* cnt = (unsigned*)(ws + CNT_OFF);
    unsigned* tb  = (unsigned*)(ws + TB_OFF);
    unsigned long long* keys = (unsigned long long*)(ws + KEYS_OFF);
    unsigned short* subhist  = (unsigned short*)(ws + SH_OFF);
    unsigned* sb             = (unsigned*)(ws + SB_OFF);

    hipMemsetAsync(cnt, 0, 64, stream);

    dim3 gs(SBLK, BATCH);
    dim3 gc(CBLK, BATCH);
    k_score  <<<gs, 256, 0, stream>>>(cls, sb, subhist);
    k_reduce <<<BATCH, 256, 0, stream>>>(subhist, tb);
    k_collect<<<gc, 256, 0, stream>>>(sb, tb, cnt, keys);
    k_final  <<<BATCH, 256, 0, stream>>>(cls, box, dir, anc, cnt, keys, out);
}

// Round 4
// 326.793 us; speedup vs baseline: 3.0165x; 1.0793x over previous
//
#include <hip/hip_runtime.h>
#include <cstdint>

#pragma clang fp contract(off)

#define HH 248
#define WW 216
#define HW (HH*WW)          // 53568 cells (divisible by 4)
#define NROW (6*HW)         // 321408
#define BATCH 16
#define NPRE 100
#define MAXNUM 50
#define NB 4096             // two-level buckets: fine for s>=0.5, coarse below
#define CAP 2048
#define SBLK 53             // blocks per batch, 1024 cells each (53*1024 >= 53568)
#define PIF 3.14159274101257324f

// ws layout (bytes):
//  [0,      64)                  cnt: 16 u32 (zeroed by k_score blk 0)
//  [64,     128)                 tb : 16 u32
//  [128,    262272)              cand keys: 16 x CAP u64
//  [262272, 262272+16*53*4096*2) subhist u16: [b][SBLK][NB]  (~6.9 MB)
#define CNT_OFF  0
#define TB_OFF   64
#define KEYS_OFF 128
#define SH_OFF   (KEYS_OFF + BATCH*CAP*8)

__device__ __forceinline__ float sigmoidf_ref(float x) {
    if (x >= 0.0f) {
        return 1.0f / (1.0f + expf(-x));
    } else {
        float e = expf(x);
        return e / (1.0f + e);
    }
}

// monotone (non-decreasing) bucket of positive-float score bits
__device__ __forceinline__ unsigned bucket_of(unsigned bits) {
    unsigned b = (bits >= 0x3F000000u) ? (2048u + ((bits - 0x3F000000u) >> 12))
                                       : (bits >> 19);
    return (b > (unsigned)(NB - 1)) ? (unsigned)(NB - 1) : b;
}

// ---- Pass 1: score + fine LDS histogram (contention-free); zero cnt for pass 3 ----
__global__ __launch_bounds__(256) void k_score(const float* __restrict__ cls,
                                               unsigned short* __restrict__ subhist,
                                               unsigned* __restrict__ cnt) {
    int t = threadIdx.x, blk = blockIdx.x, b = blockIdx.y;
    __shared__ unsigned hist[NB];   // 16 KB
    for (int i = t; i < NB; i += 256) hist[i] = 0;
    if (blk == 0 && t == 0) cnt[b] = 0;   // visible to k_collect (next dispatch)
    __syncthreads();

    int cell0 = blk * 1024 + t * 4;
    if (cell0 < HW) {               // HW%4==0 and cell0%4==0 -> full float4 in-bounds
        const float* p = cls + (size_t)b * 18 * HW;
        for (int a = 0; a < 6; ++a) {
            float4 l0 = *(const float4*)(p + (size_t)(a*3+0)*HW + cell0);
            float4 l1 = *(const float4*)(p + (size_t)(a*3+1)*HW + cell0);
            float4 l2 = *(const float4*)(p + (size_t)(a*3+2)*HW + cell0);
            unsigned b0 = __float_as_uint(sigmoidf_ref(fmaxf(l0.x, fmaxf(l1.x, l2.x))));
            unsigned b1 = __float_as_uint(sigmoidf_ref(fmaxf(l0.y, fmaxf(l1.y, l2.y))));
            unsigned b2 = __float_as_uint(sigmoidf_ref(fmaxf(l0.z, fmaxf(l1.z, l2.z))));
            unsigned b3 = __float_as_uint(sigmoidf_ref(fmaxf(l0.w, fmaxf(l1.w, l2.w))));
            atomicAdd(&hist[bucket_of(b0)], 1u);
            atomicAdd(&hist[bucket_of(b1)], 1u);
            atomicAdd(&hist[bucket_of(b2)], 1u);
            atomicAdd(&hist[bucket_of(b3)], 1u);
        }
    }
    __syncthreads();
    unsigned short* sh = subhist + (size_t)(b * SBLK + blk) * NB;
    for (int i = t; i < NB; i += 256) sh[i] = (unsigned short)hist[i];
}

// ---- Pass 2: per-batch reduce of sub-hists + threshold-bucket scan ----
__global__ __launch_bounds__(256) void k_reduce(const unsigned short* __restrict__ subhist,
                                                unsigned* __restrict__ tbo) {
    int b = blockIdx.x, t = threadIdx.x;
    __shared__ unsigned h[NB];
    __shared__ unsigned csum[256];
    const unsigned short* base = subhist + (size_t)b * SBLK * NB;
    for (int j = t; j < NB; j += 256) {
        unsigned s = 0;
        for (int k = 0; k < SBLK; ++k) s += base[(size_t)k * NB + j];
        h[j] = s;
    }
    __syncthreads();
    unsigned cs = 0;
    for (int q = 0; q < 16; ++q) cs += h[t * 16 + q];
    csum[t] = cs;
    __syncthreads();
    if (t == 0) {
        unsigned cum = 0;
        int r = 0;
        for (int u = 255; u >= 0; --u) {
            if (cum + csum[u] >= NPRE) {
                unsigned c2 = cum;
                for (int k2 = (u + 1) * 16 - 1; k2 >= u * 16; --k2) {
                    c2 += h[k2];
                    if (c2 >= NPRE) { r = k2; break; }
                }
                break;
            }
            cum += csum[u];
        }
        tbo[b] = (unsigned)r;
    }
}

// ---- Pass 3: recompute scores (cls is L3-resident), collect candidate keys ----
__global__ __launch_bounds__(256) void k_collect(const float* __restrict__ cls,
                                                 const unsigned* __restrict__ tbo,
                                                 unsigned* __restrict__ cnt,
                                                 unsigned long long* __restrict__ keys) {
    int t = threadIdx.x, blk = blockIdx.x, b = blockIdx.y;
    int cell0 = blk * 1024 + t * 4;
    if (cell0 >= HW) return;
    unsigned tb = tbo[b];
    const float* p = cls + (size_t)b * 18 * HW;
    for (int a = 0; a < 6; ++a) {
        float4 l0 = *(const float4*)(p + (size_t)(a*3+0)*HW + cell0);
        float4 l1 = *(const float4*)(p + (size_t)(a*3+1)*HW + cell0);
        float4 l2 = *(const float4*)(p + (size_t)(a*3+2)*HW + cell0);
        unsigned bs[4];
        bs[0] = __float_as_uint(sigmoidf_ref(fmaxf(l0.x, fmaxf(l1.x, l2.x))));
        bs[1] = __float_as_uint(sigmoidf_ref(fmaxf(l0.y, fmaxf(l1.y, l2.y))));
        bs[2] = __float_as_uint(sigmoidf_ref(fmaxf(l0.z, fmaxf(l1.z, l2.z))));
        bs[3] = __float_as_uint(sigmoidf_ref(fmaxf(l0.w, fmaxf(l1.w, l2.w))));
        for (int e = 0; e < 4; ++e) {
            unsigned bits = bs[e];
            if (bucket_of(bits) >= tb) {
                unsigned pos = atomicAdd(&cnt[b], 1u);
                if (pos < CAP) {
                    unsigned row = (unsigned)((cell0 + e) * 6 + a);
                    keys[(size_t)b * CAP + pos] =
                        ((unsigned long long)bits << 32) |
                        (unsigned long long)(0xFFFFFFFFu - row);
                }
            }
        }
    }
}

// ---- Pass 4: top-100 rank-select, decode, 3x NMS (bitmask + serial walk), top-50 ----
__global__ __launch_bounds__(256) void k_final(
    const float* __restrict__ cls, const float* __restrict__ box,
    const float* __restrict__ dir, const float* __restrict__ anc,
    const unsigned* __restrict__ cnt, const unsigned long long* __restrict__ keys,
    float* __restrict__ out) {
    int b = blockIdx.x, t = threadIdx.x;   // 256 threads

    __shared__ unsigned long long keyS[CAP];           // 16 KB
    __shared__ int   selRow[NPRE];
    __shared__ float bb[NPRE][7];
    __shared__ float b2d[NPRE][4];
    __shared__ float areaS[NPRE];
    __shared__ float clsS[3][NPRE];
    __shared__ float svalS[3][NPRE];
    __shared__ int   ordS[3][NPRE];
    __shared__ int   rankS[3][NPRE];
    __shared__ unsigned keepInit[3][4];
    __shared__ unsigned long long maskS[3][NPRE][2];
    __shared__ unsigned long long keepBits[3][2];
    __shared__ float flatS[3*NPRE];

    unsigned cn = cnt[b];
    int M = (cn < (unsigned)CAP) ? (int)cn : CAP;
    for (int i = t; i < M; i += 256)
        keyS[i] = keys[(size_t)b * CAP + i];
    __syncthreads();

    // exact top-100: keys unique -> ranks unique
    for (int i = t; i < M; i += 256) {
        unsigned long long k = keyS[i];
        int r = 0;
        for (int j = 0; j < M; ++j) r += (keyS[j] > k);
        if (r < NPRE) selRow[r] = (int)(0xFFFFFFFFu - (unsigned)(k & 0xFFFFFFFFull));
    }
    __syncthreads();

    // decode the 100 selected rows
    if (t < NPRE) {
        int row = selRow[t];
        int a = row % 6;
        int cell = row / 6;
        const float* cb = cls + (size_t)b * 18 * HW + cell;
        clsS[0][t] = sigmoidf_ref(cb[(size_t)(a*3+0)*HW]);
        clsS[1][t] = sigmoidf_ref(cb[(size_t)(a*3+1)*HW]);
        clsS[2][t] = sigmoidf_ref(cb[(size_t)(a*3+2)*HW]);
        const float* db = dir + (size_t)b * 12 * HW + cell;
        float d0 = db[(size_t)(a*2+0)*HW];
        float d1 = db[(size_t)(a*2+1)*HW];
        int dircls = (d1 > d0) ? 1 : 0;
        const float* pb = box + (size_t)b * 42 * HW + cell;
        float dx = pb[(size_t)(a*7+0)*HW], dy = pb[(size_t)(a*7+1)*HW], dz = pb[(size_t)(a*7+2)*HW];
        float dw = pb[(size_t)(a*7+3)*HW], dl = pb[(size_t)(a*7+4)*HW], dh = pb[(size_t)(a*7+5)*HW];
        float dr = pb[(size_t)(a*7+6)*HW];
        const float* ab = anc + (size_t)row * 7;
        float xa = ab[0], ya = ab[1], za = ab[2];
        float wa = ab[3], la = ab[4], ha = ab[5], ra = ab[6];
        float da = sqrtf(wa*wa + la*la);
        float x = dx*da + xa;
        float y = dy*da + ya;
        float z = dz*ha + za + ha*0.5f;
        float wv = wa*expf(dw);
        float lv = la*expf(dl);
        float hv = ha*expf(dh);
        z = z - hv*0.5f;
        float th0 = ra + dr;
        float lim = th0 - floorf(th0/PIF + 1.0f)*PIF;
        float theta = lim + (1.0f - (float)dircls)*PIF;
        bb[t][0]=x; bb[t][1]=y; bb[t][2]=z; bb[t][3]=wv; bb[t][4]=lv; bb[t][5]=hv; bb[t][6]=theta;
        b2d[t][0] = x - wv*0.5f;
        b2d[t][1] = y - lv*0.5f;
        b2d[t][2] = x + wv*0.5f;
        b2d[t][3] = y + lv*0.5f;
        areaS[t] = (b2d[t][2]-b2d[t][0]) * (b2d[t][3]-b2d[t][1]);
    }
    if (t < 12) keepInit[t/4][t%4] = 0u;
    __syncthreads();

    // masked scores
    for (int w = t; w < 3*NPRE; w += 256) {
        int c = w / NPRE, p = w % NPRE;
        float sc = clsS[c][p];
        svalS[c][p] = (sc > 0.1f) ? sc : -INFINITY;
    }
    __syncthreads();

    // stable descending rank per class (ties -> lower index first)
    for (int w = t; w < 3*NPRE; w += 256) {
        int c = w / NPRE, p = w % NPRE;
        float v = svalS[c][p];
        int r = 0;
        for (int j = 0; j < NPRE; ++j) {
            float vj = svalS[c][j];
            if (vj > v || (vj == v && j < p)) ++r;
        }
        ordS[c][r] = p;
        rankS[c][p] = r;
        if (v != -INFINITY) atomicOr(&keepInit[c][r >> 5], 1u << (r & 31));
    }
    __syncthreads();

    // pairwise suppression masks in sorted space (j > i, iou > thr)
    for (int w = t; w < 3*NPRE; w += 256) {
        int c = w / NPRE, i = w % NPRE;
        int pi = ordS[c][i];
        unsigned long long m0 = 0ULL, m1 = 0ULL;
        float ax1 = b2d[pi][0], ay1 = b2d[pi][1], ax2 = b2d[pi][2], ay2 = b2d[pi][3];
        float ai = areaS[pi];
        for (int j = i + 1; j < NPRE; ++j) {
            int pj = ordS[c][j];
            float x1 = fmaxf(ax1, b2d[pj][0]);
            float y1 = fmaxf(ay1, b2d[pj][1]);
            float x2 = fminf(ax2, b2d[pj][2]);
            float y2 = fminf(ay2, b2d[pj][3]);
            float inter = fmaxf(x2 - x1, 0.0f) * fmaxf(y2 - y1, 0.0f);
            float iou = inter / (ai + areaS[pj] - inter + 1e-8f);
            if (iou > 0.01f) {
                if (j < 64) m0 |= (1ULL << j);
                else        m1 |= (1ULL << (j - 64));
            }
        }
        maskS[c][i][0] = m0;
        maskS[c][i][1] = m1;
    }
    __syncthreads();

    // greedy serial walk, one lane per class
    if (t < 3) {
        int c = t;
        unsigned long long k0 = (unsigned long long)keepInit[c][0] |
                                ((unsigned long long)keepInit[c][1] << 32);
        unsigned long long k1 = (unsigned long long)keepInit[c][2] |
                                ((unsigned long long)keepInit[c][3] << 32);
        for (int i = 0; i < NPRE; ++i) {
            unsigned long long bit = (i < 64) ? (k0 >> i) : (k1 >> (i - 64));
            if (bit & 1ULL) {
                k0 &= ~maskS[c][i][0];
                k1 &= ~maskS[c][i][1];
            }
        }
        keepBits[c][0] = k0;
        keepBits[c][1] = k1;
    }
    __syncthreads();

    // flat masked score array (keep already includes validity)
    for (int w = t; w < 3*NPRE; w += 256) {
        int c = w / NPRE, p = w % NPRE;
        int r = rankS[c][p];
        unsigned long long bit = (r < 64) ? (keepBits[c][0] >> r) : (keepBits[c][1] >> (r - 64));
        flatS[w] = (bit & 1ULL) ? clsS[c][p] : -1.0f;
    }
    __syncthreads();

    // stable top-50 over 300 entries; ranks unique -> each slot written exactly once
    for (int i = t; i < 3*NPRE; i += 256) {
        float vi = flatS[i];
        int r2 = 0;
        for (int j = 0; j < 3*NPRE; ++j) {
            float vj = flatS[j];
            if (vj > vi || (vj == vi && j < i)) ++r2;
        }
        if (r2 < MAXNUM) {
            int p = i % NPRE;
            int lab = i / NPRE;
            int o = b * MAXNUM + r2;
            float* ob = out + (size_t)o * 7;
            for (int j = 0; j < 7; ++j) ob[j] = bb[p][j];
            out[BATCH*MAXNUM*7 + o] = (float)lab;
            out[BATCH*MAXNUM*8 + o] = vi;
            out[BATCH*MAXNUM*9 + o] = (vi > 0.0f) ? 1.0f : 0.0f;
        }
    }
}

extern "C" void kernel_launch(void* const* d_in, const int* in_sizes, int n_in,
                              void* d_out, int out_size, void* d_ws, size_t ws_size,
                              hipStream_t stream) {
    const float* cls = (const float*)d_in[0];
    const float* box = (const float*)d_in[1];
    const float* dir = (const float*)d_in[2];
    const float* anc = (const float*)d_in[3];
    float* out = (float*)d_out;
    char* ws = (char*)d_ws;

    unsigned* cnt = (unsigned*)(ws + CNT_OFF);
    unsigned* tb  = (unsigned*)(ws + TB_OFF);
    unsigned long long* keys = (unsigned long long*)(ws + KEYS_OFF);
    unsigned short* subhist  = (unsigned short*)(ws + SH_OFF);

    dim3 g(SBLK, BATCH);
    k_score  <<<g, 256, 0, stream>>>(cls, subhist, cnt);
    k_reduce <<<BATCH, 256, 0, stream>>>(subhist, tb);
    k_collect<<<g, 256, 0, stream>>>(cls, tb, cnt, keys);
    k_final  <<<BATCH, 256, 0, stream>>>(cls, box, dir, anc, cnt, keys, out);
}